// Round 5
// baseline (323.729 us; speedup 1.0000x reference)
//
#include <hip/hip_runtime.h>
#include <hip/hip_bf16.h>
#include <stdint.h>

// Problem dims
#define NE 8
#define NT 1024
#define NH 2048
#define NI 1408
#define NI2 (2 * NI)  // 2816

typedef __attribute__((ext_vector_type(8))) short          bf16x8;
typedef __attribute__((ext_vector_type(8))) unsigned short u16x8;
typedef __attribute__((ext_vector_type(4))) unsigned short u16x4;
typedef __attribute__((ext_vector_type(4))) float          f32x4;

__device__ __forceinline__ unsigned short f2bf(float f) {
  union { float f; uint32_t u; } v; v.f = f;
  uint32_t u = v.u;
  return (unsigned short)((u + 0x7FFFu + ((u >> 16) & 1u)) >> 16);  // RNE
}

// async global->LDS, 16B per lane. LDS dest is wave-uniform base + lane*16.
__device__ __forceinline__ void gload_lds16(const void* g, void* l) {
  __builtin_amdgcn_global_load_lds(
      (const __attribute__((address_space(1))) uint32_t*)g,
      (__attribute__((address_space(3))) uint32_t*)l, 16, 0, 0);
}

#define WAITV(n) asm volatile("s_waitcnt vmcnt(" #n ")" ::: "memory")
#define LGKM0()  asm volatile("s_waitcnt lgkmcnt(0)" ::: "memory")
#define BAR() do { __builtin_amdgcn_sched_barrier(0); \
                   __builtin_amdgcn_s_barrier();      \
                   __builtin_amdgcn_sched_barrier(0); } while (0)

// B-tile per-thread register staging: 4x16B (64B contiguous half-row)
struct BReg { u16x8 v0, v1, v2, v3; };

__device__ __forceinline__ void bload(BReg& r, const unsigned short* g) {
  r.v0 = *(const u16x8*)(g + 0);
  r.v1 = *(const u16x8*)(g + 8);
  r.v2 = *(const u16x8*)(g + 16);
  r.v3 = *(const u16x8*)(g + 24);
}
// T2 XOR applied at write time: chunk j' = (halfsel*4+j) ^ (row&7)
__device__ __forceinline__ void bwrite(unsigned short* lds, int rowB, int halfsel,
                                       const BReg& r) {
  unsigned short* base = lds + rowB * 64;
  const int x = rowB & 7;
  *(u16x8*)(base + (((halfsel * 4 + 0) ^ x) * 8)) = r.v0;
  *(u16x8*)(base + (((halfsel * 4 + 1) ^ x) * 8)) = r.v1;
  *(u16x8*)(base + (((halfsel * 4 + 2) ^ x) * 8)) = r.v2;
  *(u16x8*)(base + (((halfsel * 4 + 3) ^ x) * 8)) = r.v3;
}

// ---------------------------------------------------------------------------
// x: fp32 -> bf16 elementwise
// ---------------------------------------------------------------------------
__global__ __launch_bounds__(256) void cvt_bf16(const float* __restrict__ src,
                                                unsigned short* __restrict__ dst,
                                                int n8) {
  int i = blockIdx.x * blockDim.x + threadIdx.x;
  const int stride = gridDim.x * blockDim.x;
  for (; i < n8; i += stride) {
    const float4 f0 = ((const float4*)src)[i * 2];
    const float4 f1 = ((const float4*)src)[i * 2 + 1];
    u16x8 o;
    o[0] = f2bf(f0.x); o[1] = f2bf(f0.y); o[2] = f2bf(f0.z); o[3] = f2bf(f0.w);
    o[4] = f2bf(f1.x); o[5] = f2bf(f1.y); o[6] = f2bf(f1.z); o[7] = f2bf(f1.w);
    ((u16x8*)dst)[i] = o;
  }
}

// ---------------------------------------------------------------------------
// Transpose + cvt:  src [E][R][C] f32  ->  dst rows mapped from c, ld = R, bf16
// ilv=1: out row = ((c>>4)<<5) | (c&15) | radd   (16-col gate/up interleave)
// ---------------------------------------------------------------------------
__global__ __launch_bounds__(256) void transpose_cvt(
    const float* __restrict__ src, unsigned short* __restrict__ dst,
    int R, int C, long estride, int ilv, int radd) {
  __shared__ float tile[64][65];
  const int e  = blockIdx.z;
  const int c0 = blockIdx.x * 64;
  const int r0 = blockIdx.y * 64;
  const float* s = src + (size_t)e * R * C;
  unsigned short* d = dst + (size_t)e * estride;
  const int tid = threadIdx.x;
  const int tr  = tid >> 4;        // 0..15
  const int tc  = (tid & 15) * 4;  // 0..60
  #pragma unroll
  for (int it = 0; it < 4; ++it) {
    const int r = it * 16 + tr;
    float4 v = *(const float4*)(s + (size_t)(r0 + r) * C + c0 + tc);
    tile[r][tc + 0] = v.x; tile[r][tc + 1] = v.y;
    tile[r][tc + 2] = v.z; tile[r][tc + 3] = v.w;
  }
  __syncthreads();
  #pragma unroll
  for (int it = 0; it < 4; ++it) {
    const int oc = it * 16 + tr;
    const int c  = c0 + oc;
    const int ro = ilv ? ((((c >> 4) << 5) | (c & 15)) | radd) : c;
    u16x4 o;
    o[0] = f2bf(tile[tc + 0][oc]);
    o[1] = f2bf(tile[tc + 1][oc]);
    o[2] = f2bf(tile[tc + 2][oc]);
    o[3] = f2bf(tile[tc + 3][oc]);
    *(u16x4*)(d + (size_t)ro * R + r0 + tc) = o;
  }
}

// ---------------------------------------------------------------------------
// GEMM1 (fused gate+up): h = silu-pair(x_bf @ wcat^T)
// BM=128, BN=256, BK=64; 512 thr (8 waves 2Mx4N, wave tile 64x64); KT=32.
// A via global_load_lds 1 tile ahead; B global->reg 2 tiles ahead, ds_write
// with XOR swizzle; counted vmcnt(6)/(4); 2 phases x 16 MFMA per K-tile.
// Grid 704 = 8bx * 11by * 8e; XCD chunk = one expert.
// ---------------------------------------------------------------------------
__global__ __launch_bounds__(512, 2) void gemm_gu(
    const unsigned short* __restrict__ Ag,   // [E][1024][2048]
    const unsigned short* __restrict__ Bg,   // [E][2816][2048] interleaved
    unsigned short* __restrict__ hout) {     // [E][1024][1408]
  constexpr int KT = NH / 64;  // 32
  __shared__ __align__(16) unsigned short As[2][128 * 64];
  __shared__ __align__(16) unsigned short Bs[2][256 * 64];

  const int flat = blockIdx.x;
  const int orig = (flat & 7) * 88 + (flat >> 3);
  const int bx   = orig & 7;
  const int rest = orig >> 3;
  const int by   = rest % 11;
  const int e    = rest / 11;

  const int bm  = bx * 128;
  const int bnn = by * 256;

  const int tid  = threadIdx.x;
  const int lane = tid & 63;
  const int w    = tid >> 6;
  const int wrm  = (w >> 2) * 64;
  const int wcn  = (w & 3) * 64;

  const unsigned short* Ae = Ag + (size_t)e * NT * NH;
  const unsigned short* Be = Bg + (size_t)e * NI2 * NH;

  // A staging (gload_lds, pre-swizzled global source)
  const int l8 = lane >> 3;
  const int jx = (lane & 7) ^ l8;
  const unsigned short* aAg = Ae + (size_t)(bm + w * 16 + l8) * NH + jx * 8;

  // B reg staging: thread covers row tid>>1, 64B half (tid&1)
  const int rowB    = tid >> 1;
  const int halfsel = tid & 1;
  const unsigned short* bsrc = Be + (size_t)(bnn + rowB) * NH + halfsel * 32;

  f32x4 acc[4][4];
  #pragma unroll
  for (int i = 0; i < 4; ++i)
    #pragma unroll
    for (int j = 0; j < 4; ++j) acc[i][j] = f32x4{0.f, 0.f, 0.f, 0.f};

  const int aoff = (lane & 15) * 128 + ((((lane >> 4) << 4)) ^ ((lane & 7) << 4));

  auto stageA = [&](unsigned short* dst, int t) {
    const unsigned short* g = aAg + (size_t)t * 64;
    #pragma unroll
    for (int q = 0; q < 2; ++q)
      gload_lds16(g + (size_t)q * 8 * NH, dst + (w * 16 + q * 8) * 64);
  };

  BReg Rev, Rod;

  // prologue: A(0)->LDS0 (2 loads); B(0)->Rev, B(1)->Rod (4+4)
  stageA(As[0], 0);
  bload(Rev, bsrc);
  bload(Rod, bsrc + 64);
  WAITV(4);                 // drain A(0), B(0); leave B(1)
  bwrite(Bs[0], rowB, halfsel, Rev);
  LGKM0();
  BAR();

  auto body = [&](int tc, BReg& riss, BReg& rwr) {
    const char* Ab = (const char*)As[tc & 1] + wrm * 128;
    const char* Bb = (const char*)Bs[tc & 1] + wcn * 128;
    unsigned short* An = As[(tc + 1) & 1];
    unsigned short* Bn = Bs[(tc + 1) & 1];
    const int ta = (tc + 1 < KT) ? tc + 1 : KT - 1;
    const int tb = (tc + 2 < KT) ? tc + 2 : KT - 1;

    // ---- P1: kk=0 frags; stage A(t+1); issue B(t+2); write B(t+1)
    bf16x8 aa[4], bb[4];
    #pragma unroll
    for (int mi = 0; mi < 4; ++mi) aa[mi] = *(const bf16x8*)(Ab + mi * 2048 + aoff);
    #pragma unroll
    for (int nj = 0; nj < 4; ++nj) bb[nj] = *(const bf16x8*)(Bb + nj * 2048 + aoff);
    stageA(An, ta);
    bload(riss, bsrc + (size_t)tb * 64);
    WAITV(6);               // drain B(t+1) regs; leave A(t+1)+B(t+2)
    bwrite(Bn, rowB, halfsel, rwr);
    BAR();
    __builtin_amdgcn_s_setprio(1);
    #pragma unroll
    for (int mi = 0; mi < 4; ++mi)
      #pragma unroll
      for (int nj = 0; nj < 4; ++nj)
        acc[mi][nj] = __builtin_amdgcn_mfma_f32_16x16x32_bf16(
            aa[mi], bb[nj], acc[mi][nj], 0, 0, 0);
    __builtin_amdgcn_s_setprio(0);
    BAR();

    // ---- P2: kk=1 frags
    bf16x8 a2[4], b2[4];
    #pragma unroll
    for (int mi = 0; mi < 4; ++mi) a2[mi] = *(const bf16x8*)(Ab + mi * 2048 + (aoff ^ 64));
    #pragma unroll
    for (int nj = 0; nj < 4; ++nj) b2[nj] = *(const bf16x8*)(Bb + nj * 2048 + (aoff ^ 64));
    BAR();
    __builtin_amdgcn_s_setprio(1);
    #pragma unroll
    for (int mi = 0; mi < 4; ++mi)
      #pragma unroll
      for (int nj = 0; nj < 4; ++nj)
        acc[mi][nj] = __builtin_amdgcn_mfma_f32_16x16x32_bf16(
            a2[mi], b2[nj], acc[mi][nj], 0, 0, 0);
    __builtin_amdgcn_s_setprio(0);
    LGKM0();
    WAITV(4);               // drain A(t+1); leave B(t+2)
    BAR();
  };

  #pragma unroll 1
  for (int t = 0; t < KT; t += 2) {
    body(t, Rev, Rod);
    body(t + 1, Rod, Rev);
  }

  // epilogue: silu-pair -> h bf16 (nj=2p gate, nj=2p+1 up)
  unsigned short* he = hout + (size_t)e * NT * NI;
  const int crow = (lane >> 4) * 4;
  const int ccol = lane & 15;
  const int hcb  = by * 128 + (wcn >> 1);
  #pragma unroll
  for (int mi = 0; mi < 4; ++mi)
    #pragma unroll
    for (int p = 0; p < 2; ++p)
      #pragma unroll
      for (int j = 0; j < 4; ++j) {
        const float g = acc[mi][2 * p][j];
        const float u = acc[mi][2 * p + 1][j];
        const float sv = g / (1.0f + __expf(-g)) * u;
        const int row = bm + wrm + mi * 16 + crow + j;
        const int col = hcb + p * 16 + ccol;
        he[(size_t)row * NI + col] = f2bf(sv);
      }
}

// ---------------------------------------------------------------------------
// GEMM2: out = h @ dT^T, f32 out.
// BM=BN=256, BK=64; 512 thr (8 waves 2Mx4N, wave tile 128x64); KT=22.
// Same pipeline; 4 phases x 16 MFMA; vmcnt(8)/(4). Grid 256 = 1/CU.
// ---------------------------------------------------------------------------
__global__ __launch_bounds__(512, 2) void gemm_dn(
    const unsigned short* __restrict__ Ag,   // [E][1024][1408] h
    const unsigned short* __restrict__ Bg,   // [E][2048][1408] dT
    float* __restrict__ outp) {              // [E][1024][2048]
  constexpr int KT = NI / 64;  // 22
  __shared__ __align__(16) unsigned short As[2][256 * 64];
  __shared__ __align__(16) unsigned short Bs[2][256 * 64];

  const int flat = blockIdx.x;
  const int orig = (flat & 7) * 32 + (flat >> 3);
  const int bx   = orig & 3;
  const int rest = orig >> 2;
  const int by   = rest & 7;
  const int e    = rest >> 3;

  const int bm  = bx * 256;
  const int bnn = by * 256;

  const int tid  = threadIdx.x;
  const int lane = tid & 63;
  const int w    = tid >> 6;
  const int wrm  = (w >> 2) * 128;
  const int wcn  = (w & 3) * 64;

  const unsigned short* Ae = Ag + (size_t)e * NT * NI;
  const unsigned short* Be = Bg + (size_t)e * NH * NI;

  const int l8 = lane >> 3;
  const int jx = (lane & 7) ^ l8;
  const unsigned short* aAg = Ae + (size_t)(bm + w * 32 + l8) * NI + jx * 8;

  const int rowB    = tid >> 1;
  const int halfsel = tid & 1;
  const unsigned short* bsrc = Be + (size_t)(bnn + rowB) * NI + halfsel * 32;

  f32x4 acc[8][4];
  #pragma unroll
  for (int i = 0; i < 8; ++i)
    #pragma unroll
    for (int j = 0; j < 4; ++j) acc[i][j] = f32x4{0.f, 0.f, 0.f, 0.f};

  const int aoff = (lane & 15) * 128 + ((((lane >> 4) << 4)) ^ ((lane & 7) << 4));

  auto stageA = [&](unsigned short* dst, int t) {
    const unsigned short* g = aAg + (size_t)t * 64;
    #pragma unroll
    for (int q = 0; q < 4; ++q)
      gload_lds16(g + (size_t)q * 8 * NI, dst + (w * 32 + q * 8) * 64);
  };

  BReg Rev, Rod;

  stageA(As[0], 0);
  bload(Rev, bsrc);
  bload(Rod, bsrc + 64);
  WAITV(4);
  bwrite(Bs[0], rowB, halfsel, Rev);
  LGKM0();
  BAR();

  auto body = [&](int tc, BReg& riss, BReg& rwr) {
    const char* Ab = (const char*)As[tc & 1] + wrm * 128;
    const char* Bb = (const char*)Bs[tc & 1] + wcn * 128;
    unsigned short* An = As[(tc + 1) & 1];
    unsigned short* Bn = Bs[(tc + 1) & 1];
    const int ta = (tc + 1 < KT) ? tc + 1 : KT - 1;
    const int tb = (tc + 2 < KT) ? tc + 2 : KT - 1;

    // ---- P1: A mi0-3 kk0 + B kk0; stage A(t+1)
    bf16x8 aa[4], bb[4];
    #pragma unroll
    for (int mi = 0; mi < 4; ++mi) aa[mi] = *(const bf16x8*)(Ab + mi * 2048 + aoff);
    #pragma unroll
    for (int nj = 0; nj < 4; ++nj) bb[nj] = *(const bf16x8*)(Bb + nj * 2048 + aoff);
    stageA(An, ta);
    BAR();
    __builtin_amdgcn_s_setprio(1);
    #pragma unroll
    for (int mi = 0; mi < 4; ++mi)
      #pragma unroll
      for (int nj = 0; nj < 4; ++nj)
        acc[mi][nj] = __builtin_amdgcn_mfma_f32_16x16x32_bf16(
            aa[mi], bb[nj], acc[mi][nj], 0, 0, 0);
    __builtin_amdgcn_s_setprio(0);
    BAR();

    // ---- P2: A mi4-7 kk0; issue B(t+2)
    bf16x8 a2[4];
    #pragma unroll
    for (int mi = 0; mi < 4; ++mi) a2[mi] = *(const bf16x8*)(Ab + (4 + mi) * 2048 + aoff);
    bload(riss, bsrc + (size_t)tb * 64);
    BAR();
    __builtin_amdgcn_s_setprio(1);
    #pragma unroll
    for (int mi = 0; mi < 4; ++mi)
      #pragma unroll
      for (int nj = 0; nj < 4; ++nj)
        acc[4 + mi][nj] = __builtin_amdgcn_mfma_f32_16x16x32_bf16(
            a2[mi], bb[nj], acc[4 + mi][nj], 0, 0, 0);
    __builtin_amdgcn_s_setprio(0);
    BAR();

    // ---- P3: A mi0-3 kk1 + B kk1; write B(t+1)
    bf16x8 a3[4], b2[4];
    #pragma unroll
    for (int mi = 0; mi < 4; ++mi) a3[mi] = *(const bf16x8*)(Ab + mi * 2048 + (aoff ^ 64));
    #pragma unroll
    for (int nj = 0; nj < 4; ++nj) b2[nj] = *(const bf16x8*)(Bb + nj * 2048 + (aoff ^ 64));
    WAITV(8);               // drain B(t+1) regs; leave A(t+1)+B(t+2)
    bwrite(Bn, rowB, halfsel, rwr);
    BAR();
    __builtin_amdgcn_s_setprio(1);
    #pragma unroll
    for (int mi = 0; mi < 4; ++mi)
      #pragma unroll
      for (int nj = 0; nj < 4; ++nj)
        acc[mi][nj] = __builtin_amdgcn_mfma_f32_16x16x32_bf16(
            a3[mi], b2[nj], acc[mi][nj], 0, 0, 0);
    __builtin_amdgcn_s_setprio(0);
    BAR();

    // ---- P4: A mi4-7 kk1
    bf16x8 a4[4];
    #pragma unroll
    for (int mi = 0; mi < 4; ++mi) a4[mi] = *(const bf16x8*)(Ab + (4 + mi) * 2048 + (aoff ^ 64));
    __builtin_amdgcn_s_setprio(1);
    #pragma unroll
    for (int mi = 0; mi < 4; ++mi)
      #pragma unroll
      for (int nj = 0; nj < 4; ++nj)
        acc[4 + mi][nj] = __builtin_amdgcn_mfma_f32_16x16x32_bf16(
            a4[mi], b2[nj], acc[4 + mi][nj], 0, 0, 0);
    __builtin_amdgcn_s_setprio(0);
    LGKM0();
    WAITV(4);               // drain A(t+1); leave B(t+2)
    BAR();
  };

  #pragma unroll 1
  for (int t = 0; t < KT; t += 2) {
    body(t, Rev, Rod);
    body(t + 1, Rod, Rev);
  }

  float* oe = outp + (size_t)e * NT * NH;
  const int crow = (lane >> 4) * 4;
  const int ccol = lane & 15;
  #pragma unroll
  for (int mi = 0; mi < 8; ++mi)
    #pragma unroll
    for (int nj = 0; nj < 4; ++nj)
      #pragma unroll
      for (int j = 0; j < 4; ++j) {
        const int row = bm + wrm + mi * 16 + crow + j;
        const int col = bnn + wcn + nj * 16 + ccol;
        oe[(size_t)row * NH + col] = acc[mi][nj][j];
      }
}

// ---------------------------------------------------------------------------
extern "C" void kernel_launch(void* const* d_in, const int* in_sizes, int n_in,
                              void* d_out, int out_size, void* d_ws, size_t ws_size,
                              hipStream_t stream) {
  const float* x    = (const float*)d_in[0];  // [E][T][H]
  const float* gate = (const float*)d_in[1];  // [E][H][I]
  const float* up   = (const float*)d_in[2];  // [E][H][I]
  const float* down = (const float*)d_in[3];  // [E][I][H]
  float* out = (float*)d_out;                 // [E][T][H]

  unsigned short* x_bf = (unsigned short*)d_ws;
  unsigned short* wcat = x_bf + (size_t)NE * NT * NH;
  unsigned short* dT   = wcat + (size_t)NE * NI2 * NH;
  unsigned short* hb   = dT   + (size_t)NE * NH * NI;

  cvt_bf16<<<2048, 256, 0, stream>>>(x, x_bf, NE * NT * NH / 8);

  transpose_cvt<<<dim3(NI / 64, NH / 64, NE), 256, 0, stream>>>(
      gate, wcat, NH, NI, (long)NI2 * NH, 1, 0);
  transpose_cvt<<<dim3(NI / 64, NH / 64, NE), 256, 0, stream>>>(
      up, wcat, NH, NI, (long)NI2 * NH, 1, 16);
  transpose_cvt<<<dim3(NH / 64, NI / 64, NE), 256, 0, stream>>>(
      down, dT, NI, NH, (long)NH * NI, 0, 0);

  gemm_gu<<<704, 512, 0, stream>>>(x_bf, wcat, hb);
  gemm_dn<<<256, 512, 0, stream>>>(hb, dT, out);
}

// Round 6
// 276.793 us; speedup vs baseline: 1.1696x; 1.1696x over previous
//
#include <hip/hip_runtime.h>
#include <hip/hip_bf16.h>
#include <stdint.h>

// Problem dims
#define NE 8
#define NT 1024
#define NH 2048
#define NI 1408
#define NI2 (2 * NI)  // 2816

typedef __attribute__((ext_vector_type(8))) short          bf16x8;
typedef __attribute__((ext_vector_type(8))) unsigned short u16x8;
typedef __attribute__((ext_vector_type(4))) unsigned short u16x4;
typedef __attribute__((ext_vector_type(4))) float          f32x4;

__device__ __forceinline__ unsigned short f2bf(float f) {
  union { float f; uint32_t u; } v; v.f = f;
  uint32_t u = v.u;
  return (unsigned short)((u + 0x7FFFu + ((u >> 16) & 1u)) >> 16);  // RNE
}

// async global->LDS, 16B per lane. LDS dest is wave-uniform base + lane*16.
__device__ __forceinline__ void gload_lds16(const void* g, void* l) {
  __builtin_amdgcn_global_load_lds(
      (const __attribute__((address_space(1))) uint32_t*)g,
      (__attribute__((address_space(3))) uint32_t*)l, 16, 0, 0);
}

#define WAITV(n) asm volatile("s_waitcnt vmcnt(" #n ")" ::: "memory")
#define BAR() do { __builtin_amdgcn_sched_barrier(0); \
                   __builtin_amdgcn_s_barrier();      \
                   __builtin_amdgcn_sched_barrier(0); } while (0)

// ---------------------------------------------------------------------------
// x: fp32 -> bf16 elementwise
// ---------------------------------------------------------------------------
__global__ __launch_bounds__(256) void cvt_bf16(const float* __restrict__ src,
                                                unsigned short* __restrict__ dst,
                                                int n8) {
  int i = blockIdx.x * blockDim.x + threadIdx.x;
  const int stride = gridDim.x * blockDim.x;
  for (; i < n8; i += stride) {
    const float4 f0 = ((const float4*)src)[i * 2];
    const float4 f1 = ((const float4*)src)[i * 2 + 1];
    u16x8 o;
    o[0] = f2bf(f0.x); o[1] = f2bf(f0.y); o[2] = f2bf(f0.z); o[3] = f2bf(f0.w);
    o[4] = f2bf(f1.x); o[5] = f2bf(f1.y); o[6] = f2bf(f1.z); o[7] = f2bf(f1.w);
    ((u16x8*)dst)[i] = o;
  }
}

// ---------------------------------------------------------------------------
// Transpose + cvt:  src [E][R][C] f32  ->  dst rows mapped from c, ld = R, bf16
// ilv=1: out row = ((c>>4)<<5) | (c&15) | radd   (16-col gate/up interleave)
// ---------------------------------------------------------------------------
__global__ __launch_bounds__(256) void transpose_cvt(
    const float* __restrict__ src, unsigned short* __restrict__ dst,
    int R, int C, long estride, int ilv, int radd) {
  __shared__ float tile[64][65];
  const int e  = blockIdx.z;
  const int c0 = blockIdx.x * 64;
  const int r0 = blockIdx.y * 64;
  const float* s = src + (size_t)e * R * C;
  unsigned short* d = dst + (size_t)e * estride;
  const int tid = threadIdx.x;
  const int tr  = tid >> 4;        // 0..15
  const int tc  = (tid & 15) * 4;  // 0..60
  #pragma unroll
  for (int it = 0; it < 4; ++it) {
    const int r = it * 16 + tr;
    float4 v = *(const float4*)(s + (size_t)(r0 + r) * C + c0 + tc);
    tile[r][tc + 0] = v.x; tile[r][tc + 1] = v.y;
    tile[r][tc + 2] = v.z; tile[r][tc + 3] = v.w;
  }
  __syncthreads();
  #pragma unroll
  for (int it = 0; it < 4; ++it) {
    const int oc = it * 16 + tr;
    const int c  = c0 + oc;
    const int ro = ilv ? ((((c >> 4) << 5) | (c & 15)) | radd) : c;
    u16x4 o;
    o[0] = f2bf(tile[tc + 0][oc]);
    o[1] = f2bf(tile[tc + 1][oc]);
    o[2] = f2bf(tile[tc + 2][oc]);
    o[3] = f2bf(tile[tc + 3][oc]);
    *(u16x4*)(d + (size_t)ro * R + r0 + tc) = o;
  }
}

// ---------------------------------------------------------------------------
// 3-stage pipelined GEMM: C[e,m,n] = A[e,m,:] . B[e,n,:]  (bf16, K-contig)
// BM=128, BN=256, BK=64; 512 thr (8 waves 2Mx4N, wave tile 64x64).
// LDS: 3 x (A 16KB + B 32KB) = 144 KB.  All staging via global_load_lds.
// Per K-tile t: P1 {frag reads kk0; STAGE(t+2); BAR; 16 MFMA; BAR}
//               P2 {frag reads kk1; WAITV(6) [drains t+1, leaves t+2]; BAR;
//                   16 MFMA; BAR}
// Steady-state never waits vmcnt(0): t+1's loads fly a full tile (~800 cyc).
// T2 XOR-swizzle via pre-swizzled global source; T5 setprio; T1 XCD chunks.
// MODE 0: f32 out [E][1024][NBY*256]
// MODE 1: silu-pair bf16 out [E][1024][NBY*128] (B rows interleaved g16/u16)
// ---------------------------------------------------------------------------
template <int NBY, int KDIM, int MODE>
__global__ __launch_bounds__(512, 2) void gemm_pipe(
    const unsigned short* __restrict__ Ag,  // [E][1024][KDIM]
    const unsigned short* __restrict__ Bg,  // [E][NBY*256][KDIM]
    void* __restrict__ outp) {
  constexpr int KT    = KDIM / 64;
  constexpr int CHUNK = NBY * 8;  // blocks per XCD = one expert

  __shared__ __align__(16) unsigned short As[3][128 * 64];
  __shared__ __align__(16) unsigned short Bs[3][256 * 64];

  // XCD-chunked bijective swizzle (grid = NE*NBY*8, NE==8 XCDs)
  const int flat = blockIdx.x;
  const int orig = (flat & 7) * CHUNK + (flat >> 3);
  const int bx   = orig & 7;          // 8 M-blocks
  const int rest = orig >> 3;
  const int by   = rest % NBY;
  const int e    = rest / NBY;

  const int bm  = bx * 128;
  const int bnn = by * 256;

  const int tid  = threadIdx.x;
  const int lane = tid & 63;
  const int w    = tid >> 6;
  const int wrm  = (w >> 2) * 64;  // wave M offset
  const int wcn  = (w & 3) * 64;   // wave N offset (B rows)

  const unsigned short* Ae = Ag + (size_t)e * 1024 * KDIM;
  const unsigned short* Be = Bg + (size_t)e * (NBY * 256) * KDIM;

  // staging: per gload a wave covers 8 rows x 128B; lane l: row l>>3,
  // chunk (l&7)^(l>>3) of the global row (pre-swizzled source -> linear LDS
  // dest equals XOR-swizzled layout; frag reads apply the same XOR).
  const int l8 = lane >> 3;
  const int jx = (lane & 7) ^ l8;
  const unsigned short* aAg = Ae + (size_t)(bm  + w * 16 + l8) * KDIM + jx * 8;
  const unsigned short* aBg = Be + (size_t)(bnn + w * 32 + l8) * KDIM + jx * 8;

  f32x4 acc[4][4];
  #pragma unroll
  for (int i = 0; i < 4; ++i)
    #pragma unroll
    for (int j = 0; j < 4; ++j) acc[i][j] = f32x4{0.f, 0.f, 0.f, 0.f};

  // swizzled fragment read offset (bytes) within a 16-row frag
  const int aoff = (lane & 15) * 128 + ((((lane >> 4) << 4)) ^ ((lane & 7) << 4));

  auto STAGE = [&](unsigned short* Ad, unsigned short* Bd, int t) {
    const int kb = t * 64;
    #pragma unroll
    for (int q = 0; q < 2; ++q)
      gload_lds16(aAg + (size_t)q * 8 * KDIM + kb, Ad + (w * 16 + q * 8) * 64);
    #pragma unroll
    for (int q = 0; q < 4; ++q)
      gload_lds16(aBg + (size_t)q * 8 * KDIM + kb, Bd + (w * 32 + q * 8) * 64);
  };

  unsigned short *A0 = As[0], *A1 = As[1], *A2 = As[2];
  unsigned short *B0 = Bs[0], *B1 = Bs[1], *B2 = Bs[2];

  // prologue: stage tiles 0,1; drain tile 0 (leave tile 1 in flight)
  STAGE(A0, B0, 0);
  STAGE(A1, B1, 1);
  WAITV(6);
  BAR();

  #pragma unroll 1
  for (int t = 0; t < KT; ++t) {
    const char* Ab = (const char*)A0 + wrm * 128;
    const char* Bb = (const char*)B0 + wcn * 128;
    const bool st = (t + 2 < KT);

    // ---- P1: kk0 frags; issue STAGE(t+2)
    bf16x8 aa[4], bb[4];
    #pragma unroll
    for (int mi = 0; mi < 4; ++mi) aa[mi] = *(const bf16x8*)(Ab + mi * 2048 + aoff);
    #pragma unroll
    for (int nj = 0; nj < 4; ++nj) bb[nj] = *(const bf16x8*)(Bb + nj * 2048 + aoff);
    if (st) STAGE(A2, B2, t + 2);
    BAR();
    __builtin_amdgcn_s_setprio(1);
    #pragma unroll
    for (int mi = 0; mi < 4; ++mi)
      #pragma unroll
      for (int nj = 0; nj < 4; ++nj)
        acc[mi][nj] = __builtin_amdgcn_mfma_f32_16x16x32_bf16(
            aa[mi], bb[nj], acc[mi][nj], 0, 0, 0);
    __builtin_amdgcn_s_setprio(0);
    BAR();

    // ---- P2: kk1 frags; counted wait publishes tile t+1
    bf16x8 a2[4], b2[4];
    #pragma unroll
    for (int mi = 0; mi < 4; ++mi) a2[mi] = *(const bf16x8*)(Ab + mi * 2048 + (aoff ^ 64));
    #pragma unroll
    for (int nj = 0; nj < 4; ++nj) b2[nj] = *(const bf16x8*)(Bb + nj * 2048 + (aoff ^ 64));
    if (st) { WAITV(6); } else { WAITV(0); }
    BAR();
    __builtin_amdgcn_s_setprio(1);
    #pragma unroll
    for (int mi = 0; mi < 4; ++mi)
      #pragma unroll
      for (int nj = 0; nj < 4; ++nj)
        acc[mi][nj] = __builtin_amdgcn_mfma_f32_16x16x32_bf16(
            a2[mi], b2[nj], acc[mi][nj], 0, 0, 0);
    __builtin_amdgcn_s_setprio(0);
    BAR();

    unsigned short* tp;
    tp = A0; A0 = A1; A1 = A2; A2 = tp;
    tp = B0; B0 = B1; B1 = B2; B2 = tp;
  }

  const int crow = (lane >> 4) * 4;
  const int ccol = lane & 15;
  if constexpr (MODE == 0) {
    float* oe = (float*)outp + (size_t)e * 1024 * (NBY * 256);
    #pragma unroll
    for (int mi = 0; mi < 4; ++mi)
      #pragma unroll
      for (int nj = 0; nj < 4; ++nj)
        #pragma unroll
        for (int j = 0; j < 4; ++j) {
          const int row = bm + wrm + mi * 16 + crow + j;
          const int col = bnn + wcn + nj * 16 + ccol;
          oe[(size_t)row * (NBY * 256) + col] = acc[mi][nj][j];
        }
  } else {
    // silu-pair: frag nj=2p is gate cols, nj=2p+1 the matching up cols
    unsigned short* he = (unsigned short*)outp + (size_t)e * 1024 * (NBY * 128);
    const int hcb = by * 128 + (wcn >> 1);
    #pragma unroll
    for (int mi = 0; mi < 4; ++mi)
      #pragma unroll
      for (int p = 0; p < 2; ++p)
        #pragma unroll
        for (int j = 0; j < 4; ++j) {
          const float g = acc[mi][2 * p][j];
          const float u = acc[mi][2 * p + 1][j];
          const float sv = g / (1.0f + __expf(-g)) * u;
          const int row = bm + wrm + mi * 16 + crow + j;
          const int col = hcb + p * 16 + ccol;
          he[(size_t)row * (NBY * 128) + col] = f2bf(sv);
        }
  }
}

// ---------------------------------------------------------------------------
extern "C" void kernel_launch(void* const* d_in, const int* in_sizes, int n_in,
                              void* d_out, int out_size, void* d_ws, size_t ws_size,
                              hipStream_t stream) {
  const float* x    = (const float*)d_in[0];  // [E][T][H]
  const float* gate = (const float*)d_in[1];  // [E][H][I]
  const float* up   = (const float*)d_in[2];  // [E][H][I]
  const float* down = (const float*)d_in[3];  // [E][I][H]
  float* out = (float*)d_out;                 // [E][T][H]

  // workspace (bf16): x_bf [E][T][H], wcat [E][2I][H] (g/u 16-col interleave),
  // dT [E][H][I], h [E][T][I].
  unsigned short* x_bf = (unsigned short*)d_ws;
  unsigned short* wcat = x_bf + (size_t)NE * NT * NH;
  unsigned short* dT   = wcat + (size_t)NE * NI2 * NH;
  unsigned short* hb   = dT   + (size_t)NE * NH * NI;

  cvt_bf16<<<2048, 256, 0, stream>>>(x, x_bf, NE * NT * NH / 8);

  transpose_cvt<<<dim3(NI / 64, NH / 64, NE), 256, 0, stream>>>(
      gate, wcat, NH, NI, (long)NI2 * NH, 1, 0);
  transpose_cvt<<<dim3(NI / 64, NH / 64, NE), 256, 0, stream>>>(
      up, wcat, NH, NI, (long)NI2 * NH, 1, 16);
  transpose_cvt<<<dim3(NH / 64, NI / 64, NE), 256, 0, stream>>>(
      down, dT, NI, NH, (long)NH * NI, 0, 0);

  // GEMM1: [1024 x 2816] = x_bf @ wcat^T, fused silu-pair -> h bf16. 704 blocks.
  gemm_pipe<11, NH, 1><<<NE * 11 * 8, 512, 0, stream>>>(x_bf, wcat, hb);
  // GEMM2: [1024 x 2048] = h @ dT^T -> out f32. 512 blocks = 2.0/CU exactly.
  gemm_pipe<8, NI, 0><<<NE * 8 * 8, 512, 0, stream>>>(hb, dT, out);
}